// Round 8
// baseline (247.623 us; speedup 1.0000x reference)
//
#include <hip/hip_runtime.h>
#include <hip/hip_bf16.h>
#include <cstdint>
#include <cstddef>

#define B_ 2
#define S_ 2048
#define D_ 1024
#define H_ 16
#define HD_ 64
#define M_ 4096   // B_*S_

typedef __attribute__((ext_vector_type(8))) short short8;
typedef __attribute__((ext_vector_type(4))) short shortx4;
typedef __attribute__((ext_vector_type(4))) float floatx4;

__device__ __forceinline__ floatx4 mfma32(short8 a, short8 b, floatx4 c) {
    return __builtin_amdgcn_mfma_f32_16x16x32_bf16(a, b, c, 0, 0, 0);
}
__device__ __forceinline__ floatx4 mfma16(shortx4 a, shortx4 b, floatx4 c) {
    return __builtin_amdgcn_mfma_f32_16x16x16bf16_1k(a, b, c, 0, 0, 0);
}

// async global->LDS, 16B per lane; lds base wave-uniform, lane i lands at base + i*16B
__device__ __forceinline__ void gload_lds16(const __hip_bfloat16* g, __hip_bfloat16* lds_base) {
    __builtin_amdgcn_global_load_lds(
        (const __attribute__((address_space(1))) void*)g,
        (__attribute__((address_space(3))) void*)lds_base, 16, 0, 0);
}

// ---------------- converter: fp32 -> bf16, inputs + weights in one launch ----------------
// z=0..2: query/key/value (SZ_IN each). z=3: Wq|Wk|Wv|Wo (4*SZ_W = SZ_IN elements total).
__global__ __launch_bounds__(256) void cvt_all_kernel(
    const float* __restrict__ q, const float* __restrict__ k, const float* __restrict__ v,
    const float* __restrict__ wq, const float* __restrict__ wk,
    const float* __restrict__ wv, const float* __restrict__ wo,
    __hip_bfloat16* __restrict__ dst_in,   // qb (3*SZ_IN)
    __hip_bfloat16* __restrict__ dst_w)    // Wqb (4*SZ_W)
{
    const size_t SZ_IN = (size_t)M_ * D_;
    const size_t SZ_W  = (size_t)D_ * D_;
    int i = (blockIdx.x * 256 + threadIdx.x) * 4;
    const float* src;
    __hip_bfloat16* d;
    if (blockIdx.z < 3) {
        src = (blockIdx.z == 0 ? q : blockIdx.z == 1 ? k : v) + i;
        d = dst_in + (size_t)blockIdx.z * SZ_IN + i;
    } else {
        int w = i >> 20;                  // i / SZ_W
        int off = i & (int)(SZ_W - 1);
        src = (w == 0 ? wq : w == 1 ? wk : w == 2 ? wv : wo) + off;
        d = dst_w + (size_t)w * SZ_W + off;
    }
    float4 vv = *(const float4*)src;
    union { __hip_bfloat16 h[4]; uint2 u; } cv;
    cv.h[0] = __float2bfloat16(vv.x); cv.h[1] = __float2bfloat16(vv.y);
    cv.h[2] = __float2bfloat16(vv.z); cv.h[3] = __float2bfloat16(vv.w);
    *(uint2*)d = cv.u;
}

// ---------------- GEMM core 128x128, BK=32 (R5-proven): C = (A @ W^T + bias)*scale ----------------
// 256 threads (4 waves, 64x64 quadrant each), global_load_lds staging.
// MODE 0: bf16 row-major. MODE 1: bf16 V^T (Vt[b,h,e,s], packed 8B stores).
template <int MODE>
__device__ __forceinline__ void gemm_core(
    const __hip_bfloat16* __restrict__ A,
    const __hip_bfloat16* __restrict__ W,
    const float* __restrict__ bias,
    void* __restrict__ Cout,
    __hip_bfloat16* __restrict__ smem,   // 2*128*32 bf16 = 16 KB
    int m0, int n0, int N, float scale)
{
    __hip_bfloat16* As = smem;
    __hip_bfloat16* Bs = smem + 128 * 32;
    const int K = D_;
    const int tid  = threadIdx.x;
    const int wave = tid >> 6;
    const int lane = tid & 63;
    const int quad = lane >> 4;
    const int l15  = lane & 15;
    const int wm   = (wave & 1) * 64;
    const int wn   = (wave >> 1) * 64;
    const int srow = lane >> 2;        // 0..15
    const int scol = (lane & 3) * 8;   // 0,8,16,24

    floatx4 acc[4][4];
#pragma unroll
    for (int i = 0; i < 4; i++)
#pragma unroll
        for (int j = 0; j < 4; j++) {
            floatx4 z = {0.f, 0.f, 0.f, 0.f};
            acc[i][j] = z;
        }

    for (int k0 = 0; k0 < K; k0 += 32) {
        __syncthreads();
#pragma unroll
        for (int t = 0; t < 2; t++) {
            int r0 = wave * 32 + t * 16;
            gload_lds16(A + (size_t)(m0 + r0 + srow) * K + k0 + scol, As + r0 * 32);
            gload_lds16(W + (size_t)(n0 + r0 + srow) * K + k0 + scol, Bs + r0 * 32);
        }
        __syncthreads();

        short8 afr[4], bfr[4];
#pragma unroll
        for (int i = 0; i < 4; i++)
            afr[i] = *(const short8*)(As + (wm + i * 16 + l15) * 32 + quad * 8);
#pragma unroll
        for (int j = 0; j < 4; j++)
            bfr[j] = *(const short8*)(Bs + (wn + j * 16 + l15) * 32 + quad * 8);
#pragma unroll
        for (int i = 0; i < 4; i++)
#pragma unroll
            for (int j = 0; j < 4; j++)
                acc[i][j] = mfma32(afr[i], bfr[j], acc[i][j]);
    }

    if constexpr (MODE == 1) {
        // V^T out: Vt[((b*H+h)*64+e)*S + s]; pack r=0..3 (consecutive s) into 8B
#pragma unroll
        for (int j = 0; j < 4; j++) {
            int col = n0 + wn + j * 16 + l15;
            int h = col >> 6, e = col & 63;
            float bv = bias[col];
#pragma unroll
            for (int i = 0; i < 4; i++) {
                int s0 = m0 + wm + i * 16 + quad * 4;
                int bb = s0 >> 11, sl = s0 & 2047;
                union { __hip_bfloat16 hx[4]; uint2 u; } pk;
#pragma unroll
                for (int r = 0; r < 4; r++)
                    pk.hx[r] = __float2bfloat16(acc[i][j][r] + bv);
                *(uint2*)((__hip_bfloat16*)Cout + (((size_t)bb * H_ + h) * HD_ + e) * S_ + sl) = pk.u;
            }
        }
    } else {
#pragma unroll
        for (int j = 0; j < 4; j++) {
            int col = n0 + wn + j * 16 + l15;
            float bv = bias[col];
#pragma unroll
            for (int i = 0; i < 4; i++) {
#pragma unroll
                for (int r = 0; r < 4; r++) {
                    int rowg = m0 + wm + i * 16 + quad * 4 + r;
                    ((__hip_bfloat16*)Cout)[(size_t)rowg * N + col] =
                        __float2bfloat16((acc[i][j][r] + bv) * scale);
                }
            }
        }
    }
}

// fused QKV projections: grid (8, 32, 3). Q-path epilogue folds softmax scale*log2(e).
__global__ __launch_bounds__(256) void qkv_gemm_kernel(
    const __hip_bfloat16* __restrict__ qb, const __hip_bfloat16* __restrict__ kb,
    const __hip_bfloat16* __restrict__ vb,
    const __hip_bfloat16* __restrict__ Wqb, const __hip_bfloat16* __restrict__ Wkb,
    const __hip_bfloat16* __restrict__ Wvb,
    const float* __restrict__ bq, const float* __restrict__ bk, const float* __restrict__ bv,
    __hip_bfloat16* __restrict__ Qp, __hip_bfloat16* __restrict__ Kp,
    __hip_bfloat16* __restrict__ Vt)
{
    __shared__ __hip_bfloat16 smem[2 * 128 * 32] __attribute__((aligned(16)));
    const int z = blockIdx.z;
    const __hip_bfloat16* A = z == 0 ? qb : z == 1 ? kb : vb;
    const __hip_bfloat16* W = z == 0 ? Wqb : z == 1 ? Wkb : Wvb;
    const float* bias = z == 0 ? bq : z == 1 ? bk : bv;
    int m0 = blockIdx.y * 128, n0 = blockIdx.x * 128;
    const float kSc = 0.18033688f;  // 0.125 * log2(e), folded into Q projection
    if (z < 2) gemm_core<0>(A, W, bias, z == 0 ? (void*)Qp : (void*)Kp, smem, m0, n0, D_,
                            z == 0 ? kSc : 1.0f);
    else       gemm_core<1>(A, W, bias, (void*)Vt, smem, m0, n0, D_, 1.0f);
}

// ---------------- output projection: 64x128 tile, BK=32, fp32 out. grid (8, 64) ----------------
__global__ __launch_bounds__(256) void oproj_gemm_kernel(
    const __hip_bfloat16* __restrict__ A, const __hip_bfloat16* __restrict__ W,
    const float* __restrict__ bias, float* __restrict__ out)
{
    __shared__ __hip_bfloat16 As[64 * 32]  __attribute__((aligned(16)));
    __shared__ __hip_bfloat16 Bs[128 * 32] __attribute__((aligned(16)));
    const int K = D_, N = D_;
    const int tid  = threadIdx.x;
    const int m0   = blockIdx.y * 64;
    const int n0   = blockIdx.x * 128;
    const int wave = tid >> 6;
    const int lane = tid & 63;
    const int quad = lane >> 4;
    const int l15  = lane & 15;
    const int wm   = (wave & 1) * 32;
    const int wn   = (wave >> 1) * 64;
    const int srow = lane >> 2;
    const int scol = (lane & 3) * 8;

    floatx4 acc[2][4];
#pragma unroll
    for (int i = 0; i < 2; i++)
#pragma unroll
        for (int j = 0; j < 4; j++) {
            floatx4 z = {0.f, 0.f, 0.f, 0.f};
            acc[i][j] = z;
        }

    for (int k0 = 0; k0 < K; k0 += 32) {
        __syncthreads();
        {
            int ra = wave * 16;
            gload_lds16(A + (size_t)(m0 + ra + srow) * K + k0 + scol, As + ra * 32);
#pragma unroll
            for (int t = 0; t < 2; t++) {
                int rb = wave * 32 + t * 16;
                gload_lds16(W + (size_t)(n0 + rb + srow) * K + k0 + scol, Bs + rb * 32);
            }
        }
        __syncthreads();

        short8 afr[2], bfr[4];
#pragma unroll
        for (int i = 0; i < 2; i++)
            afr[i] = *(const short8*)(As + (wm + i * 16 + l15) * 32 + quad * 8);
#pragma unroll
        for (int j = 0; j < 4; j++)
            bfr[j] = *(const short8*)(Bs + (wn + j * 16 + l15) * 32 + quad * 8);
#pragma unroll
        for (int i = 0; i < 2; i++)
#pragma unroll
            for (int j = 0; j < 4; j++)
                acc[i][j] = mfma32(afr[i], bfr[j], acc[i][j]);
    }

#pragma unroll
    for (int j = 0; j < 4; j++) {
        int col = n0 + wn + j * 16 + l15;
        float bv = bias[col];
#pragma unroll
        for (int i = 0; i < 2; i++) {
#pragma unroll
            for (int r = 0; r < 4; r++) {
                int rowg = m0 + wm + i * 16 + quad * 4 + r;
                out[(size_t)rowg * N + col] = acc[i][j][r] + bv;
            }
        }
    }
}

// ---------------- flash attention v6: KV-tile 128, per-nt fused pipeline ----------------
// 512 threads = 8 waves; 128-row q-tile; wave w owns qrows [w*16, w*16+16).
// S^T = K·Q^T keeps P in registers in x16 A-frag layout. Scores pre-scaled by
// 0.125*log2e (folded into Q projection) -> p = exp2(s). Per-16-kv strip: QK^T mfma ->
// exp/pack -> PV mfma, interleaving VALU with MFMA. 16 kv-iters, 32 barriers total.
#define LDP 72    // Qs/Ks row stride (64 hd + pad)
#define LDV 136   // Vts row stride (128 kv + pad)
__global__ __launch_bounds__(512) void flash_attn_kernel(
    const __hip_bfloat16* __restrict__ Q,   // [B,S,D] bf16 (pre-scaled)
    const __hip_bfloat16* __restrict__ Kp,  // [B,S,D] bf16
    const __hip_bfloat16* __restrict__ Vt,  // [B,H,64,S] bf16
    const int* __restrict__ mask,           // [B,S]
    __hip_bfloat16* __restrict__ O)         // [B,S,D]
{
    __shared__ __hip_bfloat16 Qs [128 * LDP] __attribute__((aligned(16)));  // 18 KB
    __shared__ __hip_bfloat16 Ks [128 * LDP] __attribute__((aligned(16)));  // 18 KB
    __shared__ __hip_bfloat16 Vts[64 * LDV]  __attribute__((aligned(16)));  // 17 KB [hd][kv]

    const int tid  = threadIdx.x;
    const int q0   = blockIdx.x * 128;
    const int bh   = blockIdx.y;
    const int b    = bh >> 4;
    const int h    = bh & 15;
    const int wave = tid >> 6;
    const int lane = tid & 63;
    const int quad = lane >> 4;
    const int l15  = lane & 15;

    const size_t baseQ = ((size_t)b * S_ + q0) * D_ + (size_t)h * HD_;
#pragma unroll
    for (int c = tid; c < 1024; c += 512) {
        int row = c >> 3, kc = c & 7;
        *(uint4*)(Qs + row * LDP + kc * 8) = *(const uint4*)(Q + baseQ + (size_t)row * D_ + kc * 8);
    }
    __syncthreads();

    short8 qb[2];  // B-fragment: n=qrow on l15; [k-half]
    qb[0] = *(const short8*)(Qs + (wave * 16 + l15) * LDP + quad * 8);
    qb[1] = *(const short8*)(Qs + (wave * 16 + l15) * LDP + 32 + quad * 8);

    float lsum = 0.f;
    floatx4 o_acc[4];
#pragma unroll
    for (int ot = 0; ot < 4; ot++) {
        floatx4 z = {0.f, 0.f, 0.f, 0.f};
        o_acc[ot] = z;
    }

    const int* mrow = mask + b * S_;
    const __hip_bfloat16* VtBase = Vt + (size_t)bh * HD_ * S_;

    for (int kv0 = 0; kv0 < S_; kv0 += 128) {
        __syncthreads();
        const size_t baseK = ((size_t)b * S_ + kv0) * D_ + (size_t)h * HD_;
#pragma unroll
        for (int t = 0; t < 2; t++) {
            int c = tid + t * 512;
            // K tile: 128 rows x 64 hd = 1024 uint4
            int krow = c >> 3, kcol = c & 7;
            *(uint4*)(Ks + krow * LDP + kcol * 8) =
                *(const uint4*)(Kp + baseK + (size_t)krow * D_ + kcol * 8);
            // V^T tile: 64 hd rows x 128 kv = 1024 uint4
            int vrow = c >> 4, vcol = c & 15;
            *(uint4*)(Vts + vrow * LDV + vcol * 8) =
                *(const uint4*)(VtBase + (size_t)vrow * S_ + kv0 + vcol * 8);
        }
        __syncthreads();

        // per-16-kv strip: QK^T -> exp -> PV (scheduler interleaves VALU & MFMA)
#pragma unroll
        for (int nt = 0; nt < 8; nt++) {
            short8 kb0 = *(const short8*)(Ks + (nt * 16 + l15) * LDP + quad * 8);
            short8 kb1 = *(const short8*)(Ks + (nt * 16 + l15) * LDP + 32 + quad * 8);
            floatx4 s_acc = {0.f, 0.f, 0.f, 0.f};
            s_acc = mfma32(kb0, qb[0], s_acc);
            s_acc = mfma32(kb1, qb[1], s_acc);

            int4 mq = *(const int4*)(mrow + kv0 + nt * 16 + quad * 4);
            float pe0 = mq.x ? 0.f : __builtin_amdgcn_exp2f(s_acc[0]);
            float pe1 = mq.y ? 0.f : __builtin_amdgcn_exp2f(s_acc[1]);
            float pe2 = mq.z ? 0.f : __builtin_amdgcn_exp2f(s_acc[2]);
            float pe3 = mq.w ? 0.f : __builtin_amdgcn_exp2f(s_acc[3]);
            lsum += (pe0 + pe1) + (pe2 + pe3);
            union { shortx4 s4; __hip_bfloat162 b2[2]; } pk;
            pk.b2[0] = __float22bfloat162_rn({pe0, pe1});
            pk.b2[1] = __float22bfloat162_rn({pe2, pe3});

#pragma unroll
            for (int ot = 0; ot < 4; ot++) {
                shortx4 vb = *(const shortx4*)(Vts + (ot * 16 + l15) * LDV + nt * 16 + quad * 4);
                o_acc[ot] = mfma16(pk.s4, vb, o_acc[ot]);
            }
        }
    }

    // lsum lives on l15=qrow; reduce over quads (kv slices)
    lsum += __shfl_xor(lsum, 16);
    lsum += __shfl_xor(lsum, 32);

    // o_acc rows are qrow=quad*4+r — fetch matching lsum via shuffle
    const size_t baseO = ((size_t)b * S_ + q0) * D_ + (size_t)h * HD_;
#pragma unroll
    for (int r = 0; r < 4; r++) {
        float inv = 1.0f / __shfl(lsum, quad * 4 + r);
        int rowl = wave * 16 + quad * 4 + r;
#pragma unroll
        for (int ot = 0; ot < 4; ot++)
            O[baseO + (size_t)rowl * D_ + ot * 16 + l15] =
                __float2bfloat16(o_acc[ot][r] * inv);
    }
}

extern "C" void kernel_launch(void* const* d_in, const int* in_sizes, int n_in,
                              void* d_out, int out_size, void* d_ws, size_t ws_size,
                              hipStream_t stream) {
    const float* query = (const float*)d_in[0];
    const float* key   = (const float*)d_in[1];
    const float* value = (const float*)d_in[2];
    const int*   mask  = (const int*)d_in[3];
    const float* Wq    = (const float*)d_in[4];
    const float* bq    = (const float*)d_in[5];
    const float* Wk    = (const float*)d_in[6];
    const float* bk    = (const float*)d_in[7];
    const float* Wv    = (const float*)d_in[8];
    const float* bv    = (const float*)d_in[9];
    const float* Wo    = (const float*)d_in[10];
    const float* bo    = (const float*)d_in[11];
    float* out = (float*)d_out;

    const size_t SZ_IN = (size_t)M_ * D_;
    const size_t SZ_W  = (size_t)D_ * D_;
    __hip_bfloat16* qb  = (__hip_bfloat16*)d_ws;
    __hip_bfloat16* kb  = qb  + SZ_IN;
    __hip_bfloat16* vb  = kb  + SZ_IN;
    __hip_bfloat16* Wqb = vb  + SZ_IN;
    __hip_bfloat16* Wkb = Wqb + SZ_W;
    __hip_bfloat16* Wvb = Wkb + SZ_W;
    __hip_bfloat16* Wob = Wvb + SZ_W;
    __hip_bfloat16* Qp  = Wob + SZ_W;
    __hip_bfloat16* Kp  = Qp  + SZ_IN;
    __hip_bfloat16* Vt  = Kp  + SZ_IN;      // [B,H,64,S]

    // 1. convert all fp32 tensors to bf16 (z=0..2 inputs, z=3 the four weight matrices)
    cvt_all_kernel<<<dim3(SZ_IN / 1024, 1, 4), 256, 0, stream>>>(
        query, key, value, Wq, Wk, Wv, Wo, qb, Wqb);

    // 2. fused Q/K/V projections (Q pre-scaled by 0.125*log2e; V written transposed)
    qkv_gemm_kernel<<<dim3(D_ / 128, M_ / 128, 3), 256, 0, stream>>>(
        qb, kb, vb, Wqb, Wkb, Wvb, bq, bk, bv, Qp, Kp, Vt);

    // 3. flash attention (output overwrites Qp — per-block tiles disjoint)
    flash_attn_kernel<<<dim3(S_ / 128, B_ * H_), 512, 0, stream>>>(Qp, Kp, Vt, mask, Qp);

    // 4. output projection
    oproj_gemm_kernel<<<dim3(D_ / 128, M_ / 64), 256, 0, stream>>>(Qp, Wob, bo, out);
}

// Round 9
// 244.652 us; speedup vs baseline: 1.0121x; 1.0121x over previous
//
#include <hip/hip_runtime.h>
#include <hip/hip_bf16.h>
#include <cstdint>
#include <cstddef>

#define B_ 2
#define S_ 2048
#define D_ 1024
#define H_ 16
#define HD_ 64
#define M_ 4096   // B_*S_

typedef __attribute__((ext_vector_type(8))) short short8;
typedef __attribute__((ext_vector_type(4))) short shortx4;
typedef __attribute__((ext_vector_type(4))) float floatx4;

__device__ __forceinline__ floatx4 mfma32(short8 a, short8 b, floatx4 c) {
    return __builtin_amdgcn_mfma_f32_16x16x32_bf16(a, b, c, 0, 0, 0);
}
__device__ __forceinline__ floatx4 mfma16(shortx4 a, shortx4 b, floatx4 c) {
    return __builtin_amdgcn_mfma_f32_16x16x16bf16_1k(a, b, c, 0, 0, 0);
}

// async global->LDS, 16B per lane; lds base wave-uniform, lane i lands at base + i*16B
__device__ __forceinline__ void gload_lds16(const __hip_bfloat16* g, __hip_bfloat16* lds_base) {
    __builtin_amdgcn_global_load_lds(
        (const __attribute__((address_space(1))) void*)g,
        (__attribute__((address_space(3))) void*)lds_base, 16, 0, 0);
}

// ---------------- converter: fp32 -> bf16, inputs + weights in one launch ----------------
// z=0..2: query/key/value (SZ_IN each). z=3: Wq|Wk|Wv|Wo (4*SZ_W = SZ_IN elements total).
__global__ __launch_bounds__(256) void cvt_all_kernel(
    const float* __restrict__ q, const float* __restrict__ k, const float* __restrict__ v,
    const float* __restrict__ wq, const float* __restrict__ wk,
    const float* __restrict__ wv, const float* __restrict__ wo,
    __hip_bfloat16* __restrict__ dst_in,   // qb (3*SZ_IN)
    __hip_bfloat16* __restrict__ dst_w)    // Wqb (4*SZ_W)
{
    const size_t SZ_IN = (size_t)M_ * D_;
    const size_t SZ_W  = (size_t)D_ * D_;
    int i = (blockIdx.x * 256 + threadIdx.x) * 4;
    const float* src;
    __hip_bfloat16* d;
    if (blockIdx.z < 3) {
        src = (blockIdx.z == 0 ? q : blockIdx.z == 1 ? k : v) + i;
        d = dst_in + (size_t)blockIdx.z * SZ_IN + i;
    } else {
        int w = i >> 20;                  // i / SZ_W
        int off = i & (int)(SZ_W - 1);
        src = (w == 0 ? wq : w == 1 ? wk : w == 2 ? wv : wo) + off;
        d = dst_w + (size_t)w * SZ_W + off;
    }
    float4 vv = *(const float4*)src;
    union { __hip_bfloat16 h[4]; uint2 u; } cv;
    cv.h[0] = __float2bfloat16(vv.x); cv.h[1] = __float2bfloat16(vv.y);
    cv.h[2] = __float2bfloat16(vv.z); cv.h[3] = __float2bfloat16(vv.w);
    *(uint2*)d = cv.u;
}

// ---------------- GEMM core 128x128, BK=32 (R5-proven): C = (A @ W^T + bias)*scale ----------------
// 256 threads (4 waves, 64x64 quadrant each), global_load_lds staging.
// MODE 0: bf16 row-major. MODE 1: bf16 V^T (Vt[b,h,e,s], packed 8B stores).
template <int MODE>
__device__ __forceinline__ void gemm_core(
    const __hip_bfloat16* __restrict__ A,
    const __hip_bfloat16* __restrict__ W,
    const float* __restrict__ bias,
    void* __restrict__ Cout,
    __hip_bfloat16* __restrict__ smem,   // 2*128*32 bf16 = 16 KB
    int m0, int n0, int N, float scale)
{
    __hip_bfloat16* As = smem;
    __hip_bfloat16* Bs = smem + 128 * 32;
    const int K = D_;
    const int tid  = threadIdx.x;
    const int wave = tid >> 6;
    const int lane = tid & 63;
    const int quad = lane >> 4;
    const int l15  = lane & 15;
    const int wm   = (wave & 1) * 64;
    const int wn   = (wave >> 1) * 64;
    const int srow = lane >> 2;        // 0..15
    const int scol = (lane & 3) * 8;   // 0,8,16,24

    floatx4 acc[4][4];
#pragma unroll
    for (int i = 0; i < 4; i++)
#pragma unroll
        for (int j = 0; j < 4; j++) {
            floatx4 z = {0.f, 0.f, 0.f, 0.f};
            acc[i][j] = z;
        }

    for (int k0 = 0; k0 < K; k0 += 32) {
        __syncthreads();
#pragma unroll
        for (int t = 0; t < 2; t++) {
            int r0 = wave * 32 + t * 16;
            gload_lds16(A + (size_t)(m0 + r0 + srow) * K + k0 + scol, As + r0 * 32);
            gload_lds16(W + (size_t)(n0 + r0 + srow) * K + k0 + scol, Bs + r0 * 32);
        }
        __syncthreads();

        short8 afr[4], bfr[4];
#pragma unroll
        for (int i = 0; i < 4; i++)
            afr[i] = *(const short8*)(As + (wm + i * 16 + l15) * 32 + quad * 8);
#pragma unroll
        for (int j = 0; j < 4; j++)
            bfr[j] = *(const short8*)(Bs + (wn + j * 16 + l15) * 32 + quad * 8);
#pragma unroll
        for (int i = 0; i < 4; i++)
#pragma unroll
            for (int j = 0; j < 4; j++)
                acc[i][j] = mfma32(afr[i], bfr[j], acc[i][j]);
    }

    if constexpr (MODE == 1) {
        // V^T out: Vt[((b*H+h)*64+e)*S + s]; pack r=0..3 (consecutive s) into 8B
#pragma unroll
        for (int j = 0; j < 4; j++) {
            int col = n0 + wn + j * 16 + l15;
            int h = col >> 6, e = col & 63;
            float bv = bias[col];
#pragma unroll
            for (int i = 0; i < 4; i++) {
                int s0 = m0 + wm + i * 16 + quad * 4;
                int bb = s0 >> 11, sl = s0 & 2047;
                union { __hip_bfloat16 hx[4]; uint2 u; } pk;
#pragma unroll
                for (int r = 0; r < 4; r++)
                    pk.hx[r] = __float2bfloat16(acc[i][j][r] + bv);
                *(uint2*)((__hip_bfloat16*)Cout + (((size_t)bb * H_ + h) * HD_ + e) * S_ + sl) = pk.u;
            }
        }
    } else {
#pragma unroll
        for (int j = 0; j < 4; j++) {
            int col = n0 + wn + j * 16 + l15;
            float bv = bias[col];
#pragma unroll
            for (int i = 0; i < 4; i++) {
#pragma unroll
                for (int r = 0; r < 4; r++) {
                    int rowg = m0 + wm + i * 16 + quad * 4 + r;
                    ((__hip_bfloat16*)Cout)[(size_t)rowg * N + col] =
                        __float2bfloat16((acc[i][j][r] + bv) * scale);
                }
            }
        }
    }
}

// fused QKV projections: grid (8, 32, 3). Q-path epilogue folds softmax scale*log2(e).
__global__ __launch_bounds__(256) void qkv_gemm_kernel(
    const __hip_bfloat16* __restrict__ qb, const __hip_bfloat16* __restrict__ kb,
    const __hip_bfloat16* __restrict__ vb,
    const __hip_bfloat16* __restrict__ Wqb, const __hip_bfloat16* __restrict__ Wkb,
    const __hip_bfloat16* __restrict__ Wvb,
    const float* __restrict__ bq, const float* __restrict__ bk, const float* __restrict__ bv,
    __hip_bfloat16* __restrict__ Qp, __hip_bfloat16* __restrict__ Kp,
    __hip_bfloat16* __restrict__ Vt)
{
    __shared__ __hip_bfloat16 smem[2 * 128 * 32] __attribute__((aligned(16)));
    const int z = blockIdx.z;
    const __hip_bfloat16* A = z == 0 ? qb : z == 1 ? kb : vb;
    const __hip_bfloat16* W = z == 0 ? Wqb : z == 1 ? Wkb : Wvb;
    const float* bias = z == 0 ? bq : z == 1 ? bk : bv;
    int m0 = blockIdx.y * 128, n0 = blockIdx.x * 128;
    const float kSc = 0.18033688f;  // 0.125 * log2(e), folded into Q projection
    if (z < 2) gemm_core<0>(A, W, bias, z == 0 ? (void*)Qp : (void*)Kp, smem, m0, n0, D_,
                            z == 0 ? kSc : 1.0f);
    else       gemm_core<1>(A, W, bias, (void*)Vt, smem, m0, n0, D_, 1.0f);
}

// ---------------- output projection: 64x128 tile, BK=32, fp32 out. grid (8, 64) ----------------
__global__ __launch_bounds__(256) void oproj_gemm_kernel(
    const __hip_bfloat16* __restrict__ A, const __hip_bfloat16* __restrict__ W,
    const float* __restrict__ bias, float* __restrict__ out)
{
    __shared__ __hip_bfloat16 As[64 * 32]  __attribute__((aligned(16)));
    __shared__ __hip_bfloat16 Bs[128 * 32] __attribute__((aligned(16)));
    const int K = D_, N = D_;
    const int tid  = threadIdx.x;
    const int m0   = blockIdx.y * 64;
    const int n0   = blockIdx.x * 128;
    const int wave = tid >> 6;
    const int lane = tid & 63;
    const int quad = lane >> 4;
    const int l15  = lane & 15;
    const int wm   = (wave & 1) * 32;
    const int wn   = (wave >> 1) * 64;
    const int srow = lane >> 2;
    const int scol = (lane & 3) * 8;

    floatx4 acc[2][4];
#pragma unroll
    for (int i = 0; i < 2; i++)
#pragma unroll
        for (int j = 0; j < 4; j++) {
            floatx4 z = {0.f, 0.f, 0.f, 0.f};
            acc[i][j] = z;
        }

    for (int k0 = 0; k0 < K; k0 += 32) {
        __syncthreads();
        {
            int ra = wave * 16;
            gload_lds16(A + (size_t)(m0 + ra + srow) * K + k0 + scol, As + ra * 32);
#pragma unroll
            for (int t = 0; t < 2; t++) {
                int rb = wave * 32 + t * 16;
                gload_lds16(W + (size_t)(n0 + rb + srow) * K + k0 + scol, Bs + rb * 32);
            }
        }
        __syncthreads();

        short8 afr[2], bfr[4];
#pragma unroll
        for (int i = 0; i < 2; i++)
            afr[i] = *(const short8*)(As + (wm + i * 16 + l15) * 32 + quad * 8);
#pragma unroll
        for (int j = 0; j < 4; j++)
            bfr[j] = *(const short8*)(Bs + (wn + j * 16 + l15) * 32 + quad * 8);
#pragma unroll
        for (int i = 0; i < 2; i++)
#pragma unroll
            for (int j = 0; j < 4; j++)
                acc[i][j] = mfma32(afr[i], bfr[j], acc[i][j]);
    }

#pragma unroll
    for (int j = 0; j < 4; j++) {
        int col = n0 + wn + j * 16 + l15;
        float bv = bias[col];
#pragma unroll
        for (int i = 0; i < 2; i++) {
#pragma unroll
            for (int r = 0; r < 4; r++) {
                int rowg = m0 + wm + i * 16 + quad * 4 + r;
                out[(size_t)rowg * N + col] = acc[i][j][r] + bv;
            }
        }
    }
}

// ---------------- flash attention v7: v5 compute + KV register ping-pong prefetch ----------------
// 512 threads = 8 waves; 128-row q-tile; wave w owns qrows [w*16, w*16+16).
// S^T = K·Q^T keeps P in registers in x16 A-frag layout; scores pre-scaled by 0.125*log2e.
// Per 64-kv iter: issue next K/V tile loads to VGPRs -> compute current from LDS (no vmcnt
// ops inside: mask staged in LDS) -> ds_write prefetch to alt buffer -> ONE barrier.
#define LDP 72
__global__ __launch_bounds__(512) void flash_attn_kernel(
    const __hip_bfloat16* __restrict__ Q,   // [B,S,D] bf16 (pre-scaled)
    const __hip_bfloat16* __restrict__ Kp,  // [B,S,D] bf16
    const __hip_bfloat16* __restrict__ Vt,  // [B,H,64,S] bf16
    const int* __restrict__ mask,           // [B,S]
    __hip_bfloat16* __restrict__ O)         // [B,S,D]
{
    __shared__ __hip_bfloat16 Qs [128 * LDP]    __attribute__((aligned(16)));  // 18 KB
    __shared__ __hip_bfloat16 Ks [2 * 64 * LDP] __attribute__((aligned(16)));  // 18 KB
    __shared__ __hip_bfloat16 Vts[2 * 64 * LDP] __attribute__((aligned(16)));  // 18 KB [hd][kv]
    __shared__ int Ms[S_];                                                     // 8 KB

    const int tid  = threadIdx.x;
    const int q0   = blockIdx.x * 128;
    const int bh   = blockIdx.y;
    const int b    = bh >> 4;
    const int h    = bh & 15;
    const int wave = tid >> 6;
    const int lane = tid & 63;
    const int quad = lane >> 4;
    const int l15  = lane & 15;

    // stage Q tile + mask row
    const size_t baseQ = ((size_t)b * S_ + q0) * D_ + (size_t)h * HD_;
#pragma unroll
    for (int c = tid; c < 1024; c += 512) {
        int row = c >> 3, kc = c & 7;
        *(uint4*)(Qs + row * LDP + kc * 8) = *(const uint4*)(Q + baseQ + (size_t)row * D_ + kc * 8);
    }
    ((int4*)Ms)[tid] = ((const int4*)(mask + b * S_))[tid];  // 512 * 16B = 8 KB
    __syncthreads();

    short8 qb[2];  // B-fragment: n=qrow on l15; [k-half]
    qb[0] = *(const short8*)(Qs + (wave * 16 + l15) * LDP + quad * 8);
    qb[1] = *(const short8*)(Qs + (wave * 16 + l15) * LDP + 32 + quad * 8);

    float lsum = 0.f;
    floatx4 o_acc[4];
#pragma unroll
    for (int ot = 0; ot < 4; ot++) {
        floatx4 z = {0.f, 0.f, 0.f, 0.f};
        o_acc[ot] = z;
    }

    const __hip_bfloat16* KpBase = Kp + (size_t)b * S_ * D_ + (size_t)h * HD_;
    const __hip_bfloat16* VtBase = Vt + (size_t)bh * HD_ * S_;
    const int srow  = tid >> 3;        // 0..63
    const int scol8 = (tid & 7) * 8;   // 0..56

    uint4 kpre, vpre;
    auto load_kv = [&](int kv) {
        kpre = *(const uint4*)(KpBase + (size_t)(kv + srow) * D_ + scol8);
        vpre = *(const uint4*)(VtBase + (size_t)srow * S_ + kv + scol8);
    };
    auto store_kv = [&](int buf) {
        *(uint4*)(Ks  + buf * (64 * LDP) + srow * LDP + scol8) = kpre;
        *(uint4*)(Vts + buf * (64 * LDP) + srow * LDP + scol8) = vpre;
    };
    auto compute = [&](const __hip_bfloat16* KsB, const __hip_bfloat16* VtsB, int kv0) {
        // phase 1: S^T strips (8 independent MFMA chains)
        floatx4 s_acc[4];
#pragma unroll
        for (int nt = 0; nt < 4; nt++) {
            short8 kb0 = *(const short8*)(KsB + (nt * 16 + l15) * LDP + quad * 8);
            short8 kb1 = *(const short8*)(KsB + (nt * 16 + l15) * LDP + 32 + quad * 8);
            floatx4 z = {0.f, 0.f, 0.f, 0.f};
            z = mfma32(kb0, qb[0], z);
            z = mfma32(kb1, qb[1], z);
            s_acc[nt] = z;
        }
        // phase 2: exp2 + pack (mask from LDS — no vmcnt traffic)
        shortx4 pf[4];
#pragma unroll
        for (int nt = 0; nt < 4; nt++) {
            int4 mq = *(const int4*)(Ms + kv0 + nt * 16 + quad * 4);
            float pe0 = mq.x ? 0.f : __builtin_amdgcn_exp2f(s_acc[nt][0]);
            float pe1 = mq.y ? 0.f : __builtin_amdgcn_exp2f(s_acc[nt][1]);
            float pe2 = mq.z ? 0.f : __builtin_amdgcn_exp2f(s_acc[nt][2]);
            float pe3 = mq.w ? 0.f : __builtin_amdgcn_exp2f(s_acc[nt][3]);
            lsum += (pe0 + pe1) + (pe2 + pe3);
            union { shortx4 s4; __hip_bfloat162 b2[2]; } pk;
            pk.b2[0] = __float22bfloat162_rn({pe0, pe1});
            pk.b2[1] = __float22bfloat162_rn({pe2, pe3});
            pf[nt] = pk.s4;
        }
        // phase 3: O += P @ V (x16 MFMA)
#pragma unroll
        for (int nt = 0; nt < 4; nt++) {
#pragma unroll
            for (int ot = 0; ot < 4; ot++) {
                shortx4 vb = *(const shortx4*)(VtsB + (ot * 16 + l15) * LDP + nt * 16 + quad * 4);
                o_acc[ot] = mfma16(pf[nt], vb, o_acc[ot]);
            }
        }
    };

    // prologue: tile 0 -> buf 0
    load_kv(0);
    store_kv(0);
    __syncthreads();

    for (int itp = 0; itp < 16; itp++) {
        int kv0 = itp * 128;
        // even iter: compute buf0, prefetch kv0+64 -> buf1
        load_kv(kv0 + 64);
        compute(Ks, Vts, kv0);
        store_kv(1);
        __syncthreads();
        // odd iter: compute buf1, prefetch kv0+128 -> buf0
        if (itp < 15) load_kv(kv0 + 128);
        compute(Ks + 64 * LDP, Vts + 64 * LDP, kv0 + 64);
        if (itp < 15) {
            store_kv(0);
            __syncthreads();
        }
    }

    // lsum lives on l15=qrow; reduce over quads (kv slices)
    lsum += __shfl_xor(lsum, 16);
    lsum += __shfl_xor(lsum, 32);

    // o_acc rows are qrow=quad*4+r — fetch matching lsum via shuffle
    const size_t baseO = ((size_t)b * S_ + q0) * D_ + (size_t)h * HD_;
#pragma unroll
    for (int r = 0; r < 4; r++) {
        float inv = 1.0f / __shfl(lsum, quad * 4 + r);
        int rowl = wave * 16 + quad * 4 + r;
#pragma unroll
        for (int ot = 0; ot < 4; ot++)
            O[baseO + (size_t)rowl * D_ + ot * 16 + l15] =
                __float2bfloat16(o_acc[ot][r] * inv);
    }
}

extern "C" void kernel_launch(void* const* d_in, const int* in_sizes, int n_in,
                              void* d_out, int out_size, void* d_ws, size_t ws_size,
                              hipStream_t stream) {
    const float* query = (const float*)d_in[0];
    const float* key   = (const float*)d_in[1];
    const float* value = (const float*)d_in[2];
    const int*   mask  = (const int*)d_in[3];
    const float* Wq    = (const float*)d_in[4];
    const float* bq    = (const float*)d_in[5];
    const float* Wk    = (const float*)d_in[6];
    const float* bk    = (const float*)d_in[7];
    const float* Wv    = (const float*)d_in[8];
    const float* bv    = (const float*)d_in[9];
    const float* Wo    = (const float*)d_in[10];
    const float* bo    = (const float*)d_in[11];
    float* out = (float*)d_out;

    const size_t SZ_IN = (size_t)M_ * D_;
    const size_t SZ_W  = (size_t)D_ * D_;
    __hip_bfloat16* qb  = (__hip_bfloat16*)d_ws;
    __hip_bfloat16* kb  = qb  + SZ_IN;
    __hip_bfloat16* vb  = kb  + SZ_IN;
    __hip_bfloat16* Wqb = vb  + SZ_IN;
    __hip_bfloat16* Wkb = Wqb + SZ_W;
    __hip_bfloat16* Wvb = Wkb + SZ_W;
    __hip_bfloat16* Wob = Wvb + SZ_W;
    __hip_bfloat16* Qp  = Wob + SZ_W;
    __hip_bfloat16* Kp  = Qp  + SZ_IN;
    __hip_bfloat16* Vt  = Kp  + SZ_IN;      // [B,H,64,S]

    // 1. convert all fp32 tensors to bf16 (z=0..2 inputs, z=3 the four weight matrices)
    cvt_all_kernel<<<dim3(SZ_IN / 1024, 1, 4), 256, 0, stream>>>(
        query, key, value, Wq, Wk, Wv, Wo, qb, Wqb);

    // 2. fused Q/K/V projections (Q pre-scaled by 0.125*log2e; V written transposed)
    qkv_gemm_kernel<<<dim3(D_ / 128, M_ / 128, 3), 256, 0, stream>>>(
        qb, kb, vb, Wqb, Wkb, Wvb, bq, bk, bv, Qp, Kp, Vt);

    // 3. flash attention (output overwrites Qp — per-block tiles disjoint)
    flash_attn_kernel<<<dim3(S_ / 128, B_ * H_), 512, 0, stream>>>(Qp, Kp, Vt, mask, Qp);

    // 4. output projection
    oproj_gemm_kernel<<<dim3(D_ / 128, M_ / 64), 256, 0, stream>>>(Qp, Wob, bo, out);
}